// Round 2
// baseline (264.806 us; speedup 1.0000x reference)
//
#include <hip/hip_runtime.h>
#include <stdint.h>

#define EPSN 1e-9f

// Wave-level LDS fence: completes all outstanding LDS ops and stops the
// scheduler from moving ds ops across (rule #18: sched_barrier after waitcnt).
#define LDS_FENCE()                                        \
  do {                                                     \
    asm volatile("s_waitcnt lgkmcnt(0)" ::: "memory");     \
    __builtin_amdgcn_sched_barrier(0);                     \
  } while (0)

// ---------------------------------------------------------------------------
// ws layout (floats):
//   [0)       inv2_0  [4][192][256]  = 196608
//   [196608)  inv1_0s [4][48][64]    = 12288   (x1_0 at strided pixels 4i,4j)
//   [208896)  inv1_1  [4][48][64]    = 12288
//   [221184)  inv2_1  [4][48][64]    = 12288
//   total 233472 floats = 933888 bytes
// ---------------------------------------------------------------------------

__global__ __launch_bounds__(256) void norms_kernel(
    const float* __restrict__ x1_0, const float* __restrict__ x2_0,
    const float* __restrict__ x1_1, const float* __restrict__ x2_1,
    float* __restrict__ ws) {
  int p = blockIdx.x * 256 + threadIdx.x;   // grid covers exactly 233472
  const float* src; long base; int stride;
  if (p < 196608) {                         // inv2_0: all pixels of x2_0
    int b = p / 49152, r = p % 49152;
    src = x2_0; base = (long)b * 12582912 + r; stride = 49152;
  } else if (p < 208896) {                  // inv1_0 at strided pixels
    int q = p - 196608; int b = q / 3072, i = (q % 3072) / 64, j = q % 64;
    src = x1_0; base = (long)b * 12582912 + (4 * i) * 256 + 4 * j; stride = 49152;
  } else if (p < 221184) {                  // inv1_1
    int q = p - 208896; int b = q / 3072, r = q % 3072;
    src = x1_1; base = (long)b * 786432 + r; stride = 3072;
  } else {                                  // inv2_1
    int q = p - 221184; int b = q / 3072, r = q % 3072;
    src = x2_1; base = (long)b * 786432 + r; stride = 3072;
  }
  float ss = 0.f;
#pragma unroll 8
  for (int c = 0; c < 256; ++c) { float v = src[base + (long)c * stride]; ss += v * v; }
  ws[p] = 1.f / (sqrtf(ss) + EPSN);
}

// ---------------------------------------------------------------------------
// Level 0: stride 4, dilation 1. out[b,0,u,v,i,j] =
//   inv1[i,j]*inv2[4i+u-4,4j+v-4] * sum_c x1[b,c,4i,4j]*x2[b,c,4i+u-4,4j+v-4]
// Block = (b,i,u); 4 waves split channels (64 each); lane = j.
// x2 row staged in LDS [wave][8ch][264] with 4-col zero pads both sides.
// ---------------------------------------------------------------------------
__global__ __launch_bounds__(256) void corr0_kernel(
    const float* __restrict__ x1, const float* __restrict__ x2,
    const float* __restrict__ ws, float* __restrict__ out) {
  int bx = blockIdx.x;
  int u = bx % 9, i = (bx / 9) % 48, b = bx / 432;
  int y = 4 * i + u - 4;
  int tid = threadIdx.x;
  long ob = (long)b * 1741824 + (long)u * 27648 + (long)i * 64;
  if (y < 0 || y >= 192) {
    for (int idx = tid; idx < 576; idx += 256) {
      int v = idx >> 6, j = idx & 63;
      out[ob + v * 3072 + j] = 0.f;
    }
    return;
  }
  __shared__ float x2t[4][8][264];
  int w = tid >> 6, lane = tid & 63;
  {
    // zero pads: cols 0..3 and 260..263 of (w,cc); writer tids stay in-wave
    int g = tid >> 3, e = tid & 7;        // g -> (w,cc), e -> pad slot
    int ww = g >> 3, cc = g & 7;
    int col = (e < 4) ? e : (e + 256);    // 0..3 and 260..263
    x2t[ww][cc][col] = 0.f;
  }
  float acc[9];
#pragma unroll
  for (int v = 0; v < 9; ++v) acc[v] = 0.f;
  const float* x2row = x2 + (long)b * 12582912 + (long)y * 256;
  const float* x1col = x1 + (long)b * 12582912 + (long)(4 * i) * 256 + 4 * lane;

#pragma unroll 1
  for (int cc8 = 0; cc8 < 8; ++cc8) {
    int c0 = w * 64 + cc8 * 8;
    float x1v[8];
#pragma unroll
    for (int cc = 0; cc < 8; ++cc) {
      int c = c0 + cc;
      float4 f = *reinterpret_cast<const float4*>(x2row + (long)c * 49152 + 4 * lane);
      *reinterpret_cast<float4*>(&x2t[w][cc][4 + 4 * lane]) = f;
      x1v[cc] = x1col[(long)c * 49152];
    }
    LDS_FENCE();   // writes (all lanes of this wave) visible before shifted reads
#pragma unroll
    for (int cc = 0; cc < 8; ++cc) {
      const float* r = &x2t[w][cc][4 * lane];     // cols 4j-4 .. 4j+7
      float4 a = *reinterpret_cast<const float4*>(r);
      float4 bq = *reinterpret_cast<const float4*>(r + 4);
      float4 cq = *reinterpret_cast<const float4*>(r + 8);
      float xv = x1v[cc];
      acc[0] += xv * a.x;  acc[1] += xv * a.y;  acc[2] += xv * a.z;  acc[3] += xv * a.w;
      acc[4] += xv * bq.x; acc[5] += xv * bq.y; acc[6] += xv * bq.z; acc[7] += xv * bq.w;
      acc[8] += xv * cq.x;
    }
    LDS_FENCE();   // reads complete before next iteration overwrites (WAR)
  }

  __syncthreads();
  float* red = &x2t[0][0][0];               // 4*576 floats, fits in 8448
#pragma unroll
  for (int v = 0; v < 9; ++v) red[w * 576 + v * 64 + lane] = acc[v];
  __syncthreads();
  const float* i1 = ws + 196608 + b * 3072 + i * 64;
  const float* i2 = ws + (long)b * 49152 + (long)y * 256;
  for (int idx = tid; idx < 576; idx += 256) {
    int v = idx >> 6, j = idx & 63;
    float s = red[idx] + red[idx + 576] + red[idx + 1152] + red[idx + 1728];
    int col = 4 * j + v - 4;
    float i2v = (col >= 0 && col < 256) ? i2[col] : 0.f;
    out[ob + v * 3072 + j] = s * i1[j] * i2v;
  }
}

// ---------------------------------------------------------------------------
// Level 1: stride 1, dilations {1,2,3,5,9,16}. Block = (b,i,dil,u); 1 wave.
// x2 row staged as bf16x2-packed uint4 [192 cols][8ch], zero-padded +-64 cols.
// out[b,1+dI,u,v,i,j] = inv1[i,j]*inv2[y, j+(v-4)d] * sum_c x1*x2
// ---------------------------------------------------------------------------
__global__ __launch_bounds__(64) void corr1_kernel(
    const float* __restrict__ x1, const float* __restrict__ x2,
    const float* __restrict__ ws, float* __restrict__ out) {
  int bx = blockIdx.x;
  int u = bx % 9, dI = (bx / 9) % 6, i = (bx / 54) % 48, b = bx / 2592;
  const int dils[6] = {1, 2, 3, 5, 9, 16};
  int d = dils[dI];
  int y = i + (u - 4) * d;
  int lane = threadIdx.x;
  long ob = (long)b * 1741824 + (long)(1 + dI) * 248832 + (long)u * 27648 +
            (long)i * 64 + lane;
  if (y < 0 || y >= 48) {
#pragma unroll
    for (int v = 0; v < 9; ++v) out[ob + v * 3072] = 0.f;
    return;
  }
  __shared__ uint4 x2t[192];
  x2t[lane] = make_uint4(0, 0, 0, 0);
  x2t[lane + 64] = make_uint4(0, 0, 0, 0);
  x2t[lane + 128] = make_uint4(0, 0, 0, 0);
  float acc[9];
#pragma unroll
  for (int v = 0; v < 9; ++v) acc[v] = 0.f;
  const float* x2row = x2 + (long)b * 786432 + (long)y * 64 + lane;
  const float* x1row = x1 + (long)b * 786432 + (long)i * 64 + lane;

#pragma unroll 1
  for (int cc8 = 0; cc8 < 32; ++cc8) {
    float x1v[8]; uint32_t xb[8];
#pragma unroll
    for (int cc = 0; cc < 8; ++cc) {
      long c = cc8 * 8 + cc;
      xb[cc] = __float_as_uint(x2row[c * 3072]) + 0x8000u;  // round-to-bf16 (top16)
      x1v[cc] = x1row[c * 3072];
    }
    uint4 pk;
    pk.x = (xb[0] >> 16) | (xb[1] & 0xffff0000u);
    pk.y = (xb[2] >> 16) | (xb[3] & 0xffff0000u);
    pk.z = (xb[4] >> 16) | (xb[5] & 0xffff0000u);
    pk.w = (xb[6] >> 16) | (xb[7] & 0xffff0000u);
    x2t[64 + lane] = pk;                      // pads [0..63],[128..191] stay zero
    LDS_FENCE();   // own-wave writes visible before shifted cross-lane reads
#pragma unroll
    for (int v = 0; v < 9; ++v) {
      uint4 q = x2t[64 + lane + (v - 4) * d];  // col in [0,192) always
      float s;
      s  = x1v[0] * __uint_as_float(q.x << 16);
      s += x1v[1] * __uint_as_float(q.x & 0xffff0000u);
      s += x1v[2] * __uint_as_float(q.y << 16);
      s += x1v[3] * __uint_as_float(q.y & 0xffff0000u);
      s += x1v[4] * __uint_as_float(q.z << 16);
      s += x1v[5] * __uint_as_float(q.z & 0xffff0000u);
      s += x1v[6] * __uint_as_float(q.w << 16);
      s += x1v[7] * __uint_as_float(q.w & 0xffff0000u);
      acc[v] += s;
    }
    LDS_FENCE();   // reads done before next iteration's overwrite (WAR)
  }

  const float* i1 = ws + 208896 + b * 3072 + i * 64;
  const float* i2 = ws + 221184 + b * 3072 + y * 64;
  float inv1 = i1[lane];
#pragma unroll
  for (int v = 0; v < 9; ++v) {
    int col = lane + (v - 4) * d;
    float i2v = (col >= 0 && col < 64) ? i2[col] : 0.f;
    out[ob + v * 3072] = acc[v] * inv1 * i2v;   // acc==0 when col OOB (zero pads)
  }
}

extern "C" void kernel_launch(void* const* d_in, const int* in_sizes, int n_in,
                              void* d_out, int out_size, void* d_ws, size_t ws_size,
                              hipStream_t stream) {
  const float* x1_0 = (const float*)d_in[0];
  const float* x1_1 = (const float*)d_in[1];
  const float* x2_0 = (const float*)d_in[2];
  const float* x2_1 = (const float*)d_in[3];
  float* out = (float*)d_out;
  float* ws = (float*)d_ws;   // needs 933888 bytes
  norms_kernel<<<912, 256, 0, stream>>>(x1_0, x2_0, x1_1, x2_1, ws);
  corr0_kernel<<<1728, 256, 0, stream>>>(x1_0, x2_0, ws, out);
  corr1_kernel<<<10368, 64, 0, stream>>>(x1_1, x2_1, ws, out);
}

// Round 6
// 176.073 us; speedup vs baseline: 1.5040x; 1.5040x over previous
//
#include <hip/hip_runtime.h>
#include <stdint.h>

#define EPSN 1e-9f

// Wave-level LDS fence (rule #18: sched_barrier after waitcnt).
#define LDS_FENCE()                                        \
  do {                                                     \
    asm volatile("s_waitcnt lgkmcnt(0)" ::: "memory");     \
    __builtin_amdgcn_sched_barrier(0);                     \
  } while (0)

// ---------------------------------------------------------------------------
// ws layout (floats): [0) inv1_1 [4][3072]   [12288) inv2_1 [4][3072]
// ---------------------------------------------------------------------------
__global__ __launch_bounds__(256) void norms1_kernel(
    const float* __restrict__ x1_1, const float* __restrict__ x2_1,
    float* __restrict__ ws) {
  int p = blockIdx.x * 256 + threadIdx.x;     // 24576 total
  const float* src = (p < 12288) ? x1_1 : x2_1;
  int q = (p < 12288) ? p : p - 12288;        // 12288 is NOT pow2 (bugfix)
  long base = (long)(q / 3072) * 786432 + (q % 3072);
  float ss = 0.f;
#pragma unroll 8
  for (int c = 0; c < 256; ++c) { float v = src[base + (long)c * 3072]; ss += v * v; }
  ws[p] = 1.f / (sqrtf(ss) + EPSN);
}

// ---------------------------------------------------------------------------
// Level 0 (stride 4, d=1), norms fused. Block=(b,i,u), XCD-swizzled.
// Shuffle-based inner loop (no LDS in the hot loop). Lane=j.
// ---------------------------------------------------------------------------
__global__ __launch_bounds__(256) void corr0_kernel(
    const float* __restrict__ x1, const float* __restrict__ x2,
    float* __restrict__ out) {
  int bx = blockIdx.x;
  int L = (bx & 7) * 216 + (bx >> 3);         // 1728 = 8 * 216 (bijective)
  int u = L % 9, i = (L / 9) % 48, b = L / 432;
  int y = 4 * i + u - 4;
  int tid = threadIdx.x;
  long ob = (long)b * 1741824 + (long)u * 27648 + (long)i * 64;
  if (y < 0 || y >= 192) {
    for (int idx = tid; idx < 576; idx += 256)
      out[ob + (idx >> 6) * 3072 + (idx & 63)] = 0.f;
    return;
  }
  __shared__ float red[4][14][64];
  __shared__ float inv2s[264];                 // pads [0..3],[260..263] = 0
  __shared__ float inv1s[64];
  int w = tid >> 6, lane = tid & 63;
  float acc4 = 0.f, acc5 = 0.f, acc6 = 0.f, acc7 = 0.f;
  float aL0 = 0.f, aL1 = 0.f, aL2 = 0.f, aL3 = 0.f, a8 = 0.f;
  float sq0 = 0.f, sq1 = 0.f, sq2 = 0.f, sq3 = 0.f, s1 = 0.f;
  const float* x2row = x2 + (long)b * 12582912 + (long)y * 256 + 4 * lane;
  const float* x1p   = x1 + (long)b * 12582912 + (long)(4 * i) * 256 + 4 * lane;
#pragma unroll 8
  for (int cc = 0; cc < 64; ++cc) {
    long off = (long)(w * 64 + cc) * 49152;
    float4 f = *reinterpret_cast<const float4*>(x2row + off);
    float xv = x1p[off];
    float xr = __shfl_down(xv, 1);            // x1 of lane j+1
    float xl = __shfl_up(xv, 1);              // x1 of lane j-1
    sq0 += f.x * f.x; sq1 += f.y * f.y; sq2 += f.z * f.z; sq3 += f.w * f.w;
    s1  += xv * xv;
    aL0 += xr * f.x; aL1 += xr * f.y; aL2 += xr * f.z; aL3 += xr * f.w;
    acc4 += xv * f.x; acc5 += xv * f.y; acc6 += xv * f.z; acc7 += xv * f.w;
    a8  += xl * f.x;
  }
  // realign: acc[v<4](j) lives at lane j-1; acc[8](j) lives at lane j+1.
  float o0 = __shfl_up(aL0, 1), o1 = __shfl_up(aL1, 1);
  float o2 = __shfl_up(aL2, 1), o3 = __shfl_up(aL3, 1);
  float o8 = __shfl_down(a8, 1);
  // (lane-0 / lane-63 stale values map to OOB cols -> zeroed by inv2s pads)
  red[w][0][lane] = o0;   red[w][1][lane] = o1;   red[w][2][lane] = o2;
  red[w][3][lane] = o3;   red[w][4][lane] = acc4; red[w][5][lane] = acc5;
  red[w][6][lane] = acc6; red[w][7][lane] = acc7; red[w][8][lane] = o8;
  red[w][9][lane] = sq0;  red[w][10][lane] = sq1; red[w][11][lane] = sq2;
  red[w][12][lane] = sq3; red[w][13][lane] = s1;
  __syncthreads();
  {
    int comp = tid & 3, jj = tid >> 2;        // col = tid (0..255)
    float ss = red[0][9 + comp][jj] + red[1][9 + comp][jj] +
               red[2][9 + comp][jj] + red[3][9 + comp][jj];
    inv2s[4 + tid] = 1.f / (sqrtf(ss) + EPSN);
    if (tid < 4) { inv2s[tid] = 0.f; inv2s[260 + tid] = 0.f; }
    if (tid < 64) {
      float t = red[0][13][tid] + red[1][13][tid] +
                red[2][13][tid] + red[3][13][tid];
      inv1s[tid] = 1.f / (sqrtf(t) + EPSN);
    }
  }
  __syncthreads();
  for (int idx = tid; idx < 576; idx += 256) {
    int v = idx >> 6, j = idx & 63;
    float s = red[0][v][j] + red[1][v][j] + red[2][v][j] + red[3][v][j];
    out[ob + v * 3072 + j] = s * inv1s[j] * inv2s[4 * j + v];  // col=4j+v-4
  }
}

// ---------------------------------------------------------------------------
// Level 1 (round-2 PASSING implementation; only ws offsets + XCD swizzle new).
// Block=(b,i,dI,u), 1 wave. x2 row bf16x2-packed in LDS [192 cols][8ch],
// zero-padded +-64 cols.
// ---------------------------------------------------------------------------
__global__ __launch_bounds__(64) void corr1_kernel(
    const float* __restrict__ x1, const float* __restrict__ x2,
    const float* __restrict__ ws, float* __restrict__ out) {
  int bx = blockIdx.x;
  int L = (bx & 7) * 1296 + (bx >> 3);        // 10368 = 8 * 1296 (bijective)
  int u = L % 9, dI = (L / 9) % 6, i = (L / 54) % 48, b = L / 2592;
  const int dils[6] = {1, 2, 3, 5, 9, 16};
  int d = dils[dI];
  int y = i + (u - 4) * d;
  int lane = threadIdx.x;
  long ob = (long)b * 1741824 + (long)(1 + dI) * 248832 + (long)u * 27648 +
            (long)i * 64 + lane;
  if (y < 0 || y >= 48) {
#pragma unroll
    for (int v = 0; v < 9; ++v) out[ob + v * 3072] = 0.f;
    return;
  }
  __shared__ uint4 x2t[192];
  x2t[lane] = make_uint4(0, 0, 0, 0);
  x2t[lane + 64] = make_uint4(0, 0, 0, 0);
  x2t[lane + 128] = make_uint4(0, 0, 0, 0);
  float acc[9];
#pragma unroll
  for (int v = 0; v < 9; ++v) acc[v] = 0.f;
  const float* x2row = x2 + (long)b * 786432 + (long)y * 64 + lane;
  const float* x1row = x1 + (long)b * 786432 + (long)i * 64 + lane;

#pragma unroll 1
  for (int cc8 = 0; cc8 < 32; ++cc8) {
    float x1v[8]; uint32_t xb[8];
#pragma unroll
    for (int cc = 0; cc < 8; ++cc) {
      long c = cc8 * 8 + cc;
      xb[cc] = __float_as_uint(x2row[c * 3072]) + 0x8000u;  // round-to-bf16 (top16)
      x1v[cc] = x1row[c * 3072];
    }
    uint4 pk;
    pk.x = (xb[0] >> 16) | (xb[1] & 0xffff0000u);
    pk.y = (xb[2] >> 16) | (xb[3] & 0xffff0000u);
    pk.z = (xb[4] >> 16) | (xb[5] & 0xffff0000u);
    pk.w = (xb[6] >> 16) | (xb[7] & 0xffff0000u);
    x2t[64 + lane] = pk;                      // pads [0..63],[128..191] stay zero
    LDS_FENCE();   // own-wave writes visible before shifted cross-lane reads
#pragma unroll
    for (int v = 0; v < 9; ++v) {
      uint4 q = x2t[64 + lane + (v - 4) * d];  // col in [0,192) always
      float s;
      s  = x1v[0] * __uint_as_float(q.x << 16);
      s += x1v[1] * __uint_as_float(q.x & 0xffff0000u);
      s += x1v[2] * __uint_as_float(q.y << 16);
      s += x1v[3] * __uint_as_float(q.y & 0xffff0000u);
      s += x1v[4] * __uint_as_float(q.z << 16);
      s += x1v[5] * __uint_as_float(q.z & 0xffff0000u);
      s += x1v[6] * __uint_as_float(q.w << 16);
      s += x1v[7] * __uint_as_float(q.w & 0xffff0000u);
      acc[v] += s;
    }
    LDS_FENCE();   // reads done before next iteration's overwrite (WAR)
  }

  const float* i1 = ws + b * 3072 + i * 64;
  const float* i2 = ws + 12288 + b * 3072 + y * 64;
  float inv1 = i1[lane];
#pragma unroll
  for (int v = 0; v < 9; ++v) {
    int col = lane + (v - 4) * d;
    float i2v = (col >= 0 && col < 64) ? i2[col] : 0.f;
    out[ob + v * 3072] = acc[v] * inv1 * i2v;   // acc==0 when col OOB (zero pads)
  }
}

extern "C" void kernel_launch(void* const* d_in, const int* in_sizes, int n_in,
                              void* d_out, int out_size, void* d_ws, size_t ws_size,
                              hipStream_t stream) {
  const float* x1_0 = (const float*)d_in[0];
  const float* x1_1 = (const float*)d_in[1];
  const float* x2_0 = (const float*)d_in[2];
  const float* x2_1 = (const float*)d_in[3];
  float* out = (float*)d_out;
  float* ws = (float*)d_ws;                   // 98304 bytes used
  norms1_kernel<<<96, 256, 0, stream>>>(x1_1, x2_1, ws);
  corr0_kernel<<<1728, 256, 0, stream>>>(x1_0, x2_0, out);
  corr1_kernel<<<10368, 64, 0, stream>>>(x1_1, x2_1, ws, out);
}